// Round 14
// baseline (817.982 us; speedup 1.0000x reference)
//
#include <hip/hip_runtime.h>
#include <stdint.h>
#include <stddef.h>

#define KH   512
#define DF   3072
#define EPSF 1e-5f
#define PPB  8            // positions per tile
#define ROWS 48           // PPB*6
#define NT   12           // tiles per persistent block (24576/8/256)
#define TSS  516          // Ts row stride (floats), padded
#define ABYTES (ROWS * 1024)
#define SBYTES (PPB * 1024)

typedef __attribute__((ext_vector_type(4))) float f32x4;
typedef __attribute__((ext_vector_type(8))) short bf16x8;

__device__ __forceinline__ unsigned short f2bf(float f) {
  union { float f; unsigned u; } c; c.f = f;
  unsigned u = c.u;
  u += 0x7fffu + ((u >> 16) & 1u);     // RNE
  return (unsigned short)(u >> 16);
}
__device__ __forceinline__ unsigned short f2bf_trunc(float f) {
  union { float f; unsigned u; } c; c.f = f;
  return (unsigned short)(c.u >> 16);
}
__device__ __forceinline__ float bf2f(unsigned short u) {
  union { unsigned u; float f; } c; c.u = ((unsigned)u) << 16;
  return c.f;
}

// Weight images (verified R5 layout): region A (0): alpha*gamma,
// region B (+512KB): beta_w*gamma.
// byte(f,s) = (f>>2)*65536 + s*4096 + (f&3)*1024 + (h*16+co)*16 + e*2, f = o>>4.
__global__ __launch_bounds__(256) void prep_w(const float* __restrict__ cw,
                                              const float* __restrict__ cb,
                                              const float* __restrict__ nw,
                                              const float* __restrict__ nb,
                                              unsigned char* __restrict__ wbt,
                                              float* __restrict__ c12) {
  const int o = blockIdx.x;
  const int t = threadIdx.x;
  const int wn = o >> 6, nn = (o >> 4) & 3, co = o & 15;
  float c1 = 0.f, c2 = 0.f;
  for (int k = t; k < KH; k += 256) {
    float w0 = cw[o * 1024 + 2 * k];
    float w1 = cw[o * 1024 + 2 * k + 1];
    float a  = w0 - w1;
    float g  = nw[k], b = nb[k];
    int s = k >> 5, kin = k & 31, h = kin >> 3, e = kin & 7;
    size_t base = (size_t)(((wn * 16 + s) * 4 + nn)) * 1024 + (h * 16 + co) * 16 + e * 2;
    *(unsigned short*)(wbt + base)          = f2bf(a * g);    // alpha*gamma
    *(unsigned short*)(wbt + base + 524288) = f2bf(w1 * g);   // beta_w*gamma
    float tt = a + 6.f * w1;
    c1 += tt * b;
    c2 += tt * g;
  }
  #pragma unroll
  for (int off = 32; off >= 1; off >>= 1) {
    c1 += __shfl_xor(c1, off);
    c2 += __shfl_xor(c2, off);
  }
  __shared__ float s1[4], s2[4];
  int wid = t >> 6, lane = t & 63;
  if (lane == 0) { s1[wid] = c1; s2[wid] = c2; }
  __syncthreads();
  if (t == 0) {
    c12[o]      = s1[0] + s1[1] + s1[2] + s1[3] + cb[o];
    c12[KH + o] = s2[0] + s2[1] + s2[2] + s2[3];
  }
}

// LN stats + As/Sx fill for one position (producer wave pw), from q registers.
__device__ __forceinline__ void stats_fill(const f32x4* q, unsigned char* Ab,
                                           unsigned char* Sb, float* stb,
                                           int pw, int lane) {
  float vv[48];
  #pragma unroll
  for (int i = 0; i < 12; i++) {
    vv[4*i] = q[i].x; vv[4*i+1] = q[i].y; vv[4*i+2] = q[i].z; vv[4*i+3] = q[i].w;
  }
  float s = 0.f, sq = 0.f;
  #pragma unroll
  for (int i = 0; i < 48; i++) { s += vv[i]; sq += vv[i] * vv[i]; }
  #pragma unroll
  for (int off = 32; off >= 1; off >>= 1) {
    s  += __shfl_xor(s,  off);
    sq += __shfl_xor(sq, off);
  }
  float mean = s * (1.f / 3072.f);
  float var  = sq * (1.f / 3072.f) - mean * mean;
  float rstd = rsqrtf(var + EPSF);
  if (lane == 0) { stb[2 * pw] = mean; stb[2 * pw + 1] = rstd; }
  #pragma unroll
  for (int d = 0; d < 6; d++) {
    int row = pw * 6 + d;
    bf16x8 v;
    #pragma unroll
    for (int g = 0; g < 8; g++) v[g] = (short)f2bf_trunc(vv[g * 6 + d]);
    *(bf16x8*)(Ab + row * 1024 + ((lane ^ (row & 7)) << 4)) = v;
  }
  bf16x8 sv;
  #pragma unroll
  for (int g = 0; g < 8; g++) {
    float ss = vv[g*6] + vv[g*6+1] + vv[g*6+2] + vv[g*6+3] + vv[g*6+4] + vv[g*6+5];
    sv[g] = (short)f2bf_trunc(ss);
  }
  *(bf16x8*)(Sb + pw * 1024 + ((lane ^ (pw & 7)) << 4)) = sv;
}

// Coalesced store of one position's finished out-panel row (producer wave pw).
__device__ __forceinline__ void store_out_panel(const unsigned char* Ab,
                                                float* ob, int pw, int lane) {
  #pragma unroll
  for (int jj = 0; jj < 12; jj++) {
    int c0 = jj * 256 + lane * 4;
    int o0 = c0 / 6;
    int d0 = c0 - o0 * 6;
    f32x4 ov;
    #pragma unroll
    for (int e = 0; e < 4; e++) {
      int d = d0 + e, o = o0;
      if (d >= 6) { d -= 6; o += 1; }
      int row  = pw * 6 + d;
      int byte = row * 1024 + ((((o >> 3) ^ (row & 7)) << 4)) + (o & 7) * 2;
      ov[e] = bf2f(*(const unsigned short*)(Ab + byte));
    }
    *(f32x4*)(ob + c0) = ov;
  }
}

// Persistent producer/consumer block: 16 waves. Waves 0-7 (consumers) run the
// GEMM + in-place RMW epilogue continuously; waves 8-15 (producers) stream
// HBM (store finished panel t-1, load+fill panel t+1). One barrier per tile.
__global__ __launch_bounds__(1024, 4) void fused_main(
    const float* __restrict__ x,
    const unsigned char* __restrict__ wbt,
    const float* __restrict__ c12,
    float* __restrict__ out)
{
  __shared__ unsigned char As_[2 * ABYTES];   // 96 KB: raw-x -> out panel (bf16)
  __shared__ unsigned char Sx_[2 * SBYTES];   // 16 KB: color-sum panel
  __shared__ float Ts[PPB * TSS];             // 16.1 KB term2 (consumer-wave-local)
  __shared__ float st[2][PPB * 2];            // mean/rstd dbuf

  const int tid  = threadIdx.x;
  const int lane = tid & 63;
  const int wid  = tid >> 6;       // 0..15
  const int pw   = wid & 7;
  const bool isProd = wid >= 8;
  const int co   = lane & 15;
  const int h    = lane >> 4;
  const int rvb  = h << 2;
  const size_t tile0 = (size_t)blockIdx.x * NT;

  // ---- pipeline fill: producers load+fill tile 0 into buffer 0 ----
  if (isProd) {
    f32x4 q[12];
    const float* xr = x + (tile0 * PPB + pw) * DF + lane * 48;
    #pragma unroll
    for (int i = 0; i < 12; i++) q[i] = *(const f32x4*)(xr + i * 4);
    stats_fill(q, As_, Sx_, st[0], pw, lane);
  }
  __syncthreads();

  for (int t = 0; t < NT; ++t) {
    if (!isProd) {
      // ================= CONSUMER: GEMM + RMW epilogue on tile t =========
      const unsigned char* Ab = As_ + (size_t)(t & 1) * ABYTES;
      const unsigned char* Sb = Sx_ + (size_t)(t & 1) * SBYTES;
      const float* stb = st[t & 1];
      const unsigned char* wA = wbt + (size_t)pw * 65536;

      f32x4 acc1[3][4];
      #pragma unroll
      for (int m = 0; m < 3; m++)
        #pragma unroll
        for (int n = 0; n < 4; n++) acc1[m][n] = (f32x4){0.f, 0.f, 0.f, 0.f};

      int arow[3], ar7[3];
      #pragma unroll
      for (int m = 0; m < 3; m++) {
        int row = m * 16 + co;
        arow[m] = row * 1024;  ar7[m] = row & 7;
      }

      { // term1: 48x512 over K=512; A/B register double-buffered
        bf16x8 bvA[4], bvB[4], afA[3], afB[3];
        #pragma unroll
        for (int n = 0; n < 4; n++)
          bvA[n] = *(const bf16x8*)(wA + n * 1024 + lane * 16);
        #pragma unroll
        for (int m = 0; m < 3; m++)
          afA[m] = *(const bf16x8*)(Ab + arow[m] + ((h ^ ar7[m]) << 4));

        #pragma unroll 1
        for (int s = 0; s < 16; s += 2) {
          {
            int g6 = (s + 1) * 4 + h;
            #pragma unroll
            for (int m = 0; m < 3; m++)
              afB[m] = *(const bf16x8*)(Ab + arow[m] + ((g6 ^ ar7[m]) << 4));
            const unsigned char* pn = wA + (size_t)(s + 1) * 4096;
            #pragma unroll
            for (int n = 0; n < 4; n++)
              bvB[n] = *(const bf16x8*)(pn + n * 1024 + lane * 16);
          }
          __builtin_amdgcn_s_setprio(1);
          #pragma unroll
          for (int m = 0; m < 3; m++)
            #pragma unroll
            for (int n = 0; n < 4; n++)
              acc1[m][n] = __builtin_amdgcn_mfma_f32_16x16x32_bf16(afA[m], bvA[n], acc1[m][n], 0, 0, 0);
          __builtin_amdgcn_s_setprio(0);
          if (s + 2 < 16) {
            int g6 = (s + 2) * 4 + h;
            #pragma unroll
            for (int m = 0; m < 3; m++)
              afA[m] = *(const bf16x8*)(Ab + arow[m] + ((g6 ^ ar7[m]) << 4));
            const unsigned char* pn2 = wA + (size_t)(s + 2) * 4096;
            #pragma unroll
            for (int n = 0; n < 4; n++)
              bvA[n] = *(const bf16x8*)(pn2 + n * 1024 + lane * 16);
          }
          __builtin_amdgcn_s_setprio(1);
          #pragma unroll
          for (int m = 0; m < 3; m++)
            #pragma unroll
            for (int n = 0; n < 4; n++)
              acc1[m][n] = __builtin_amdgcn_mfma_f32_16x16x32_bf16(afB[m], bvB[n], acc1[m][n], 0, 0, 0);
          __builtin_amdgcn_s_setprio(0);
        }
      }

      { // term2: 8x512 over K=512; same-wave o-slice -> Ts (wave-local)
        f32x4 acc2[4];
        #pragma unroll
        for (int n = 0; n < 4; n++) acc2[n] = (f32x4){0.f, 0.f, 0.f, 0.f};
        const unsigned char* wB2 = wbt + 524288 + (size_t)pw * 65536;
        const int sxr = (co & 7);
        bf16x8 cA[4], cB[4], a2A, a2B;
        #pragma unroll
        for (int n = 0; n < 4; n++)
          cA[n] = *(const bf16x8*)(wB2 + n * 1024 + lane * 16);
        a2A = *(const bf16x8*)(Sb + sxr * 1024 + ((h ^ sxr) << 4));

        #pragma unroll 1
        for (int s = 0; s < 16; s += 2) {
          {
            int g6 = (s + 1) * 4 + h;
            a2B = *(const bf16x8*)(Sb + sxr * 1024 + ((g6 ^ sxr) << 4));
            const unsigned char* pn = wB2 + (size_t)(s + 1) * 4096;
            #pragma unroll
            for (int n = 0; n < 4; n++)
              cB[n] = *(const bf16x8*)(pn + n * 1024 + lane * 16);
          }
          __builtin_amdgcn_s_setprio(1);
          #pragma unroll
          for (int n = 0; n < 4; n++)
            acc2[n] = __builtin_amdgcn_mfma_f32_16x16x32_bf16(a2A, cA[n], acc2[n], 0, 0, 0);
          __builtin_amdgcn_s_setprio(0);
          if (s + 2 < 16) {
            int g6 = (s + 2) * 4 + h;
            a2A = *(const bf16x8*)(Sb + sxr * 1024 + ((g6 ^ sxr) << 4));
            const unsigned char* pn2 = wB2 + (size_t)(s + 2) * 4096;
            #pragma unroll
            for (int n = 0; n < 4; n++)
              cA[n] = *(const bf16x8*)(pn2 + n * 1024 + lane * 16);
          }
          __builtin_amdgcn_s_setprio(1);
          #pragma unroll
          for (int n = 0; n < 4; n++)
            acc2[n] = __builtin_amdgcn_mfma_f32_16x16x32_bf16(a2B, cB[n], acc2[n], 0, 0, 0);
          __builtin_amdgcn_s_setprio(0);
        }
        if (h < 2) {   // C rows 0..7 = positions; 8..15 aliased duplicates
          #pragma unroll
          for (int n = 0; n < 4; n++)
            #pragma unroll
            for (int v = 0; v < 4; v++)
              Ts[(rvb + v) * TSS + pw * 64 + n * 16 + co] = acc2[n][v];
        }
      }

      { // RMW epilogue: Ab[j][o] <- bf16(x + relu(h))  (in-place, R4-proven)
        unsigned char* AbW = (unsigned char*)Ab;
        #pragma unroll
        for (int n = 0; n < 4; n++) {
          const int o = pw * 64 + n * 16 + co;
          const float C1 = c12[o];
          const float C2 = c12[KH + o];
          const int swzo = o >> 3;
          const int ob2 = (o & 7) * 2;
          #pragma unroll
          for (int m = 0; m < 3; m++) {
            #pragma unroll
            for (int v = 0; v < 4; v++) {
              int j  = m * 16 + rvb + v;
              int pl = j / 6;
              float mean = stb[2 * pl], rstd = stb[2 * pl + 1];
              float t2   = Ts[pl * TSS + o];
              int byte = j * 1024 + (((swzo ^ (j & 7)) << 4)) + ob2;
              unsigned short rx = *(const unsigned short*)(AbW + byte);
              float hh = fmaxf(rstd * (acc1[m][n][v] + t2) + C1 - mean * rstd * C2, 0.f);
              *(unsigned short*)(AbW + byte) = f2bf(bf2f(rx) + hh);
            }
          }
        }
      }
    } else {
      // ================= PRODUCER: store panel t-1, load+fill panel t+1 ===
      f32x4 q[12];
      if (t < NT - 1) {          // T14: issue loads first, HBM latency hides
        const float* xr = x + ((tile0 + t + 1) * PPB + pw) * DF + lane * 48;
        #pragma unroll
        for (int i = 0; i < 12; i++) q[i] = *(const f32x4*)(xr + i * 4);
      }
      if (t > 0) {
        const unsigned char* Ap = As_ + (size_t)((t - 1) & 1) * ABYTES;
        float* ob = out + ((tile0 + t - 1) * PPB + pw) * DF;
        store_out_panel(Ap, ob, pw, lane);
      }
      if (t < NT - 1) {
        unsigned char* Ab = As_ + (size_t)((t + 1) & 1) * ABYTES;
        unsigned char* Sb = Sx_ + (size_t)((t + 1) & 1) * SBYTES;
        stats_fill(q, Ab, Sb, st[(t + 1) & 1], pw, lane);
      }
    }
    __syncthreads();      // one barrier per tile phase
  }

  // ---- pipeline drain: store last tile's panel ----
  if (isProd) {
    const unsigned char* Ap = As_ + (size_t)((NT - 1) & 1) * ABYTES;
    float* ob = out + ((tile0 + NT - 1) * PPB + pw) * DF;
    store_out_panel(Ap, ob, pw, lane);
  }
}

extern "C" void kernel_launch(void* const* d_in, const int* in_sizes, int n_in,
                              void* d_out, int out_size, void* d_ws, size_t ws_size,
                              hipStream_t stream) {
  (void)n_in; (void)out_size; (void)ws_size;
  const float* x  = (const float*)d_in[0];
  const float* cw = (const float*)d_in[1];
  const float* cb = (const float*)d_in[2];
  const float* nw = (const float*)d_in[3];
  const float* nb = (const float*)d_in[4];
  float* out = (float*)d_out;

  unsigned char* wbt = (unsigned char*)d_ws;                    // 1 MB images
  float* c12 = (float*)((char*)d_ws + (size_t)1024 * 1024);     // 4 KB

  prep_w<<<512, 256, 0, stream>>>(cw, cb, nw, nb, wbt, c12);

  const int R = in_sizes[0] / DF;            // 24576 positions
  fused_main<<<R / (PPB * NT), 1024, 0, stream>>>(x, wbt, c12, out);
}

// Round 15
// 552.013 us; speedup vs baseline: 1.4818x; 1.4818x over previous
//
#include <hip/hip_runtime.h>
#include <stdint.h>
#include <stddef.h>

#define KH   512
#define DF   3072
#define EPSF 1e-5f
#define PPB  8            // positions per tile
#define ROWS 48           // PPB*6
#define NT   12           // tiles per persistent block (24576/8/256)
#define TSS  516          // Ts row stride (floats), padded
#define ABYTES (ROWS * 1024)
#define SBYTES (PPB * 1024)

typedef __attribute__((ext_vector_type(4))) float f32x4;
typedef __attribute__((ext_vector_type(8))) short bf16x8;

__device__ __forceinline__ unsigned short f2bf(float f) {
  union { float f; unsigned u; } c; c.f = f;
  unsigned u = c.u;
  u += 0x7fffu + ((u >> 16) & 1u);     // RNE
  return (unsigned short)(u >> 16);
}
__device__ __forceinline__ unsigned short f2bf_trunc(float f) {
  union { float f; unsigned u; } c; c.f = f;
  return (unsigned short)(c.u >> 16);
}
__device__ __forceinline__ float bf2f(unsigned short u) {
  union { unsigned u; float f; } c; c.u = ((unsigned)u) << 16;
  return c.f;
}

// Weight images (verified R5 layout): region A (0): alpha*gamma,
// region B (+512KB): beta_w*gamma.
// byte(f,s) = (f>>2)*65536 + s*4096 + (f&3)*1024 + (h*16+co)*16 + e*2, f = o>>4.
__global__ __launch_bounds__(256) void prep_w(const float* __restrict__ cw,
                                              const float* __restrict__ cb,
                                              const float* __restrict__ nw,
                                              const float* __restrict__ nb,
                                              unsigned char* __restrict__ wbt,
                                              float* __restrict__ c12) {
  const int o = blockIdx.x;
  const int t = threadIdx.x;
  const int wn = o >> 6, nn = (o >> 4) & 3, co = o & 15;
  float c1 = 0.f, c2 = 0.f;
  for (int k = t; k < KH; k += 256) {
    float w0 = cw[o * 1024 + 2 * k];
    float w1 = cw[o * 1024 + 2 * k + 1];
    float a  = w0 - w1;
    float g  = nw[k], b = nb[k];
    int s = k >> 5, kin = k & 31, h = kin >> 3, e = kin & 7;
    size_t base = (size_t)(((wn * 16 + s) * 4 + nn)) * 1024 + (h * 16 + co) * 16 + e * 2;
    *(unsigned short*)(wbt + base)          = f2bf(a * g);    // alpha*gamma
    *(unsigned short*)(wbt + base + 524288) = f2bf(w1 * g);   // beta_w*gamma
    float tt = a + 6.f * w1;
    c1 += tt * b;
    c2 += tt * g;
  }
  #pragma unroll
  for (int off = 32; off >= 1; off >>= 1) {
    c1 += __shfl_xor(c1, off);
    c2 += __shfl_xor(c2, off);
  }
  __shared__ float s1[4], s2[4];
  int wid = t >> 6, lane = t & 63;
  if (lane == 0) { s1[wid] = c1; s2[wid] = c2; }
  __syncthreads();
  if (t == 0) {
    c12[o]      = s1[0] + s1[1] + s1[2] + s1[3] + cb[o];
    c12[KH + o] = s2[0] + s2[1] + s2[2] + s2[3];
  }
}

// Load one position's contiguous row segment into q[12] (lane = 48 floats).
#define LOAD_Q(tt, p) do {                                                    \
  const float* xr_ = x + ((tile0 + (size_t)(tt)) * PPB + (p)) * DF + lane * 48; \
  _Pragma("unroll")                                                           \
  for (int i_ = 0; i_ < 12; i_++) q[i_] = *(const f32x4*)(xr_ + i_ * 4);      \
} while (0)

// LN stats + As/Sx fill for position p, straight from q (no vv[] expansion).
#define FILL_Q(Ab, Sb, stb, p) do {                                           \
  float s_ = 0.f, sq_ = 0.f;                                                  \
  _Pragma("unroll")                                                           \
  for (int i_ = 0; i_ < 12; i_++) {                                           \
    s_  += q[i_].x + q[i_].y + q[i_].z + q[i_].w;                             \
    sq_ += q[i_].x*q[i_].x + q[i_].y*q[i_].y + q[i_].z*q[i_].z + q[i_].w*q[i_].w; \
  }                                                                           \
  _Pragma("unroll")                                                           \
  for (int off_ = 32; off_ >= 1; off_ >>= 1) {                                \
    s_  += __shfl_xor(s_,  off_);                                             \
    sq_ += __shfl_xor(sq_, off_);                                             \
  }                                                                           \
  float mean_ = s_ * (1.f / 3072.f);                                          \
  float var_  = sq_ * (1.f / 3072.f) - mean_ * mean_;                         \
  float rstd_ = rsqrtf(var_ + EPSF);                                          \
  if (lane == 0) { (stb)[2 * (p)] = mean_; (stb)[2 * (p) + 1] = rstd_; }      \
  _Pragma("unroll")                                                           \
  for (int d_ = 0; d_ < 6; d_++) {                                            \
    int row_ = (p) * 6 + d_;                                                  \
    bf16x8 v_;                                                                \
    _Pragma("unroll")                                                         \
    for (int g_ = 0; g_ < 8; g_++) {                                          \
      int e_ = g_ * 6 + d_;                                                   \
      v_[g_] = (short)f2bf_trunc(q[e_ >> 2][e_ & 3]);                         \
    }                                                                         \
    *(bf16x8*)((Ab) + row_ * 1024 + ((lane ^ (row_ & 7)) << 4)) = v_;         \
  }                                                                           \
  {                                                                           \
    bf16x8 sv_;                                                               \
    _Pragma("unroll")                                                         \
    for (int g_ = 0; g_ < 8; g_++) {                                          \
      float ss_ = 0.f;                                                        \
      _Pragma("unroll")                                                       \
      for (int d_ = 0; d_ < 6; d_++) {                                        \
        int e_ = g_ * 6 + d_;                                                 \
        ss_ += q[e_ >> 2][e_ & 3];                                            \
      }                                                                       \
      sv_[g_] = (short)f2bf_trunc(ss_);                                       \
    }                                                                         \
    *(bf16x8*)((Sb) + (p) * 1024 + ((lane ^ ((p) & 7)) << 4)) = sv_;          \
  }                                                                           \
} while (0)

// Coalesced store of one finished position row (reads out-panel from LDS).
__device__ __forceinline__ void store_out_panel(const unsigned char* Ab,
                                                float* ob, int p, int lane) {
  #pragma unroll
  for (int jj = 0; jj < 12; jj++) {
    int c0 = jj * 256 + lane * 4;
    int o0 = c0 / 6;
    int d0 = c0 - o0 * 6;
    f32x4 ov;
    #pragma unroll
    for (int e = 0; e < 4; e++) {
      int d = d0 + e, o = o0;
      if (d >= 6) { d -= 6; o += 1; }
      int row  = p * 6 + d;
      int byte = row * 1024 + ((((o >> 3) ^ (row & 7)) << 4)) + (o & 7) * 2;
      ov[e] = bf2f(*(const unsigned short*)(Ab + byte));
    }
    *(f32x4*)(ob + c0) = ov;
  }
}

// Persistent producer/consumer: 768 threads = 12 waves.
// Waves 0-7 (consumers): GEMM + in-place RMW epilogue, continuously.
// Waves 8-11 (producers): per phase, for each of 2 owned positions:
// issue x-load(t+1) -> store panel(t-1) -> fill panel(t+1). One barrier/phase.
__global__ __launch_bounds__(768, 3) void fused_main(
    const float* __restrict__ x,
    const unsigned char* __restrict__ wbt,
    const float* __restrict__ c12,
    float* __restrict__ out)
{
  __shared__ unsigned char As_[2 * ABYTES];   // 96 KB: raw-x -> out panel (bf16)
  __shared__ unsigned char Sx_[2 * SBYTES];   // 16 KB: color-sum panel
  __shared__ float Ts[PPB * TSS];             // 16.5 KB term2 (consumer-wave-local)
  __shared__ float st[2][PPB * 2];            // mean/rstd dbuf

  const int tid  = threadIdx.x;
  const int lane = tid & 63;
  const int wid  = tid >> 6;       // 0..11
  const bool isProd = wid >= 8;
  const int pw   = wid & 7;        // consumer: o-slice; producer: wave 0..3
  const int co   = lane & 15;
  const int h    = lane >> 4;
  const int rvb  = h << 2;
  const size_t tile0 = (size_t)blockIdx.x * NT;

  // ---- pipeline fill: producers fill tile 0 into buffer 0 ----
  if (isProd) {
    #pragma unroll
    for (int pp = 0; pp < 2; ++pp) {
      const int p = (wid - 8) * 2 + pp;
      f32x4 q[12];
      LOAD_Q(0, p);
      FILL_Q(As_, Sx_, st[0], p);
    }
  }
  __syncthreads();

  for (int t = 0; t < NT; ++t) {
    if (!isProd) {
      // ================= CONSUMER: GEMM + RMW epilogue on tile t =========
      const unsigned char* Ab = As_ + (size_t)(t & 1) * ABYTES;
      const unsigned char* Sb = Sx_ + (size_t)(t & 1) * SBYTES;
      const float* stb = st[t & 1];
      const unsigned char* wA = wbt + (size_t)pw * 65536;

      f32x4 acc1[3][4];
      #pragma unroll
      for (int m = 0; m < 3; m++)
        #pragma unroll
        for (int n = 0; n < 4; n++) acc1[m][n] = (f32x4){0.f, 0.f, 0.f, 0.f};

      int arow[3], ar7[3];
      #pragma unroll
      for (int m = 0; m < 3; m++) {
        int row = m * 16 + co;
        arow[m] = row * 1024;  ar7[m] = row & 7;
      }

      { // term1: 48x512 over K=512; A/B register double-buffered
        bf16x8 bvA[4], bvB[4], afA[3], afB[3];
        #pragma unroll
        for (int n = 0; n < 4; n++)
          bvA[n] = *(const bf16x8*)(wA + n * 1024 + lane * 16);
        #pragma unroll
        for (int m = 0; m < 3; m++)
          afA[m] = *(const bf16x8*)(Ab + arow[m] + ((h ^ ar7[m]) << 4));

        #pragma unroll 1
        for (int s = 0; s < 16; s += 2) {
          {
            int g6 = (s + 1) * 4 + h;
            #pragma unroll
            for (int m = 0; m < 3; m++)
              afB[m] = *(const bf16x8*)(Ab + arow[m] + ((g6 ^ ar7[m]) << 4));
            const unsigned char* pn = wA + (size_t)(s + 1) * 4096;
            #pragma unroll
            for (int n = 0; n < 4; n++)
              bvB[n] = *(const bf16x8*)(pn + n * 1024 + lane * 16);
          }
          __builtin_amdgcn_s_setprio(1);
          #pragma unroll
          for (int m = 0; m < 3; m++)
            #pragma unroll
            for (int n = 0; n < 4; n++)
              acc1[m][n] = __builtin_amdgcn_mfma_f32_16x16x32_bf16(afA[m], bvA[n], acc1[m][n], 0, 0, 0);
          __builtin_amdgcn_s_setprio(0);
          if (s + 2 < 16) {
            int g6 = (s + 2) * 4 + h;
            #pragma unroll
            for (int m = 0; m < 3; m++)
              afA[m] = *(const bf16x8*)(Ab + arow[m] + ((g6 ^ ar7[m]) << 4));
            const unsigned char* pn2 = wA + (size_t)(s + 2) * 4096;
            #pragma unroll
            for (int n = 0; n < 4; n++)
              bvA[n] = *(const bf16x8*)(pn2 + n * 1024 + lane * 16);
          }
          __builtin_amdgcn_s_setprio(1);
          #pragma unroll
          for (int m = 0; m < 3; m++)
            #pragma unroll
            for (int n = 0; n < 4; n++)
              acc1[m][n] = __builtin_amdgcn_mfma_f32_16x16x32_bf16(afB[m], bvB[n], acc1[m][n], 0, 0, 0);
          __builtin_amdgcn_s_setprio(0);
        }
      }

      { // term2: 8x512 over K=512; same-wave o-slice -> Ts (wave-local)
        f32x4 acc2[4];
        #pragma unroll
        for (int n = 0; n < 4; n++) acc2[n] = (f32x4){0.f, 0.f, 0.f, 0.f};
        const unsigned char* wB2 = wbt + 524288 + (size_t)pw * 65536;
        const int sxr = (co & 7);
        bf16x8 cA[4], cB[4], a2A, a2B;
        #pragma unroll
        for (int n = 0; n < 4; n++)
          cA[n] = *(const bf16x8*)(wB2 + n * 1024 + lane * 16);
        a2A = *(const bf16x8*)(Sb + sxr * 1024 + ((h ^ sxr) << 4));

        #pragma unroll 1
        for (int s = 0; s < 16; s += 2) {
          {
            int g6 = (s + 1) * 4 + h;
            a2B = *(const bf16x8*)(Sb + sxr * 1024 + ((g6 ^ sxr) << 4));
            const unsigned char* pn = wB2 + (size_t)(s + 1) * 4096;
            #pragma unroll
            for (int n = 0; n < 4; n++)
              cB[n] = *(const bf16x8*)(pn + n * 1024 + lane * 16);
          }
          __builtin_amdgcn_s_setprio(1);
          #pragma unroll
          for (int n = 0; n < 4; n++)
            acc2[n] = __builtin_amdgcn_mfma_f32_16x16x32_bf16(a2A, cA[n], acc2[n], 0, 0, 0);
          __builtin_amdgcn_s_setprio(0);
          if (s + 2 < 16) {
            int g6 = (s + 2) * 4 + h;
            a2A = *(const bf16x8*)(Sb + sxr * 1024 + ((g6 ^ sxr) << 4));
            const unsigned char* pn2 = wB2 + (size_t)(s + 2) * 4096;
            #pragma unroll
            for (int n = 0; n < 4; n++)
              cA[n] = *(const bf16x8*)(pn2 + n * 1024 + lane * 16);
          }
          __builtin_amdgcn_s_setprio(1);
          #pragma unroll
          for (int n = 0; n < 4; n++)
            acc2[n] = __builtin_amdgcn_mfma_f32_16x16x32_bf16(a2B, cB[n], acc2[n], 0, 0, 0);
          __builtin_amdgcn_s_setprio(0);
        }
        if (h < 2) {   // C rows 0..7 = positions; 8..15 aliased duplicates
          #pragma unroll
          for (int n = 0; n < 4; n++)
            #pragma unroll
            for (int v = 0; v < 4; v++)
              Ts[(rvb + v) * TSS + pw * 64 + n * 16 + co] = acc2[n][v];
        }
      }

      { // RMW epilogue: Ab[j][o] <- bf16(x + relu(h))  (in-place, R5-proven)
        unsigned char* AbW = (unsigned char*)Ab;
        #pragma unroll
        for (int n = 0; n < 4; n++) {
          const int o = pw * 64 + n * 16 + co;
          const float C1 = c12[o];
          const float C2 = c12[KH + o];
          const int swzo = o >> 3;
          const int ob2 = (o & 7) * 2;
          #pragma unroll
          for (int m = 0; m < 3; m++) {
            #pragma unroll
            for (int v = 0; v < 4; v++) {
              int j  = m * 16 + rvb + v;
              int pl = j / 6;
              float mean = stb[2 * pl], rstd = stb[2 * pl + 1];
              float t2   = Ts[pl * TSS + o];
              int byte = j * 1024 + (((swzo ^ (j & 7)) << 4)) + ob2;
              unsigned short rx = *(const unsigned short*)(AbW + byte);
              float hh = fmaxf(rstd * (acc1[m][n][v] + t2) + C1 - mean * rstd * C2, 0.f);
              *(unsigned short*)(AbW + byte) = f2bf(bf2f(rx) + hh);
            }
          }
        }
      }
    } else {
      // ===== PRODUCER: per owned position: load(t+1) -> store(t-1) -> fill(t+1)
      #pragma unroll 1
      for (int pp = 0; pp < 2; ++pp) {
        const int p = (wid - 8) * 2 + pp;
        f32x4 q[12];
        if (t < NT - 1) LOAD_Q(t + 1, p);          // in flight during store
        if (t > 0) {
          const unsigned char* Ap = As_ + (size_t)((t - 1) & 1) * ABYTES;
          float* ob = out + ((tile0 + t - 1) * PPB + p) * DF;
          store_out_panel(Ap, ob, p, lane);        // reads old rows first
        }
        if (t < NT - 1) {
          unsigned char* Ab = As_ + (size_t)((t + 1) & 1) * ABYTES;
          unsigned char* Sb = Sx_ + (size_t)((t + 1) & 1) * SBYTES;
          FILL_Q(Ab, Sb, st[(t + 1) & 1], p);      // then overwrites them
        }
      }
    }
    __syncthreads();      // one barrier per tile phase
  }

  // ---- pipeline drain: producers store the last tile's panel ----
  if (isProd) {
    #pragma unroll
    for (int pp = 0; pp < 2; ++pp) {
      const int p = (wid - 8) * 2 + pp;
      const unsigned char* Ap = As_ + (size_t)((NT - 1) & 1) * ABYTES;
      float* ob = out + ((tile0 + NT - 1) * PPB + p) * DF;
      store_out_panel(Ap, ob, p, lane);
    }
  }
}

extern "C" void kernel_launch(void* const* d_in, const int* in_sizes, int n_in,
                              void* d_out, int out_size, void* d_ws, size_t ws_size,
                              hipStream_t stream) {
  (void)n_in; (void)out_size; (void)ws_size;
  const float* x  = (const float*)d_in[0];
  const float* cw = (const float*)d_in[1];
  const float* cb = (const float*)d_in[2];
  const float* nw = (const float*)d_in[3];
  const float* nb = (const float*)d_in[4];
  float* out = (float*)d_out;

  unsigned char* wbt = (unsigned char*)d_ws;                    // 1 MB images
  float* c12 = (float*)((char*)d_ws + (size_t)1024 * 1024);     // 4 KB

  prep_w<<<512, 256, 0, stream>>>(cw, cb, nw, nb, wbt, c12);

  const int R = in_sizes[0] / DF;            // 24576 positions
  fused_main<<<R / (PPB * NT), 768, 0, stream>>>(x, wbt, c12, out);
}

// Round 16
// 233.434 us; speedup vs baseline: 3.5041x; 2.3647x over previous
//
#include <hip/hip_runtime.h>
#include <stdint.h>
#include <stddef.h>

#define KH   512
#define DF   3072
#define EPSF 1e-5f
#define PPB  8            // positions per block
#define ROWS 48           // PPB*6
#define TSS  516          // Ts row stride (floats), padded

typedef __attribute__((ext_vector_type(4))) float f32x4;
typedef __attribute__((ext_vector_type(2))) float f32x2;
typedef __attribute__((ext_vector_type(8))) short bf16x8;

__device__ __forceinline__ unsigned short f2bf(float f) {
  union { float f; unsigned u; } c; c.f = f;
  unsigned u = c.u;
  u += 0x7fffu + ((u >> 16) & 1u);     // RNE
  return (unsigned short)(u >> 16);
}
__device__ __forceinline__ unsigned short f2bf_trunc(float f) {
  union { float f; unsigned u; } c; c.f = f;
  return (unsigned short)(c.u >> 16);  // truncation: 1 op
}
__device__ __forceinline__ float bf2f(unsigned short u) {
  union { unsigned u; float f; } c; c.u = ((unsigned)u) << 16;
  return c.f;
}

// Weight images (verified R5 layout): region A (0): alpha*gamma,
// region B (+512KB): beta_w*gamma.
// byte(f,s) = (f>>2)*65536 + s*4096 + (f&3)*1024 + (h*16+co)*16 + e*2, f = o>>4.
// Per-wave per-step fragment read = contiguous coalesced 1KB dwordx4 each.
__global__ __launch_bounds__(256) void prep_w(const float* __restrict__ cw,
                                              const float* __restrict__ cb,
                                              const float* __restrict__ nw,
                                              const float* __restrict__ nb,
                                              unsigned char* __restrict__ wbt,
                                              float* __restrict__ c12) {
  const int o = blockIdx.x;
  const int t = threadIdx.x;
  const int wn = o >> 6, nn = (o >> 4) & 3, co = o & 15;
  float c1 = 0.f, c2 = 0.f;
  for (int k = t; k < KH; k += 256) {
    float w0 = cw[o * 1024 + 2 * k];
    float w1 = cw[o * 1024 + 2 * k + 1];
    float a  = w0 - w1;
    float g  = nw[k], b = nb[k];
    int s = k >> 5, kin = k & 31, h = kin >> 3, e = kin & 7;
    size_t base = (size_t)(((wn * 16 + s) * 4 + nn)) * 1024 + (h * 16 + co) * 16 + e * 2;
    *(unsigned short*)(wbt + base)          = f2bf(a * g);    // alpha*gamma
    *(unsigned short*)(wbt + base + 524288) = f2bf(w1 * g);   // beta_w*gamma
    float tt = a + 6.f * w1;
    c1 += tt * b;
    c2 += tt * g;
  }
  #pragma unroll
  for (int off = 32; off >= 1; off >>= 1) {
    c1 += __shfl_xor(c1, off);
    c2 += __shfl_xor(c2, off);
  }
  __shared__ float s1[4], s2[4];
  int wid = t >> 6, lane = t & 63;
  if (lane == 0) { s1[wid] = c1; s2[wid] = c2; }
  __syncthreads();
  if (t == 0) {
    c12[o]      = s1[0] + s1[1] + s1[2] + s1[3] + cb[o];
    c12[KH + o] = s2[0] + s2[1] + s2[2] + s2[3];
  }
}

// Block: 8 positions (48 rows) x 512 o. 512 threads = 8 waves; wave wid owns
// position wid (prologue) and o-slice wid*64..+64 (GEMMs + epilogue).
// ONE barrier. Order: prologue(+prefetch bvA,cA) -> term2 -> term1 -> epilogue
// (term2 first: its entry loads are prefetched pre-barrier; its Ts writes
// retire long before the epilogue reads them).
__global__ __launch_bounds__(512, 4) void fused_main(
    const float* __restrict__ x,
    const unsigned char* __restrict__ wbt,
    const float* __restrict__ c12,
    float* __restrict__ out)
{
  __shared__ unsigned char As[ROWS * 1024];   // 48 KB raw-x panel (bf16, swizzled)
  __shared__ unsigned char Sx[PPB * 1024];    // 8 KB raw color-sum panel
  __shared__ float Ts[PPB * TSS];             // 16.1 KB term2 (f32)
  __shared__ float st[PPB * 2];

  const int tid  = threadIdx.x;
  const int lane = tid & 63;
  const int wid  = tid >> 6;     // 0..7 : o-slice AND position owner
  const int co   = lane & 15;
  const int h    = lane >> 4;
  const int rvb  = h << 2;
  const size_t r0 = (size_t)blockIdx.x * PPB;

  const unsigned char* wA  = wbt + (size_t)wid * 65536;
  const unsigned char* wB2 = wbt + 524288 + (size_t)wid * 65536;
  bf16x8 bvA[4], bvB[4];
  bf16x8 cA[4], cB[4];

  // ---- fused prologue: wave wid owns position r0+wid ----
  {
    const float* xr = x + (size_t)(r0 + wid) * DF + lane * 48;
    f32x4 q[12];
    #pragma unroll
    for (int i = 0; i < 12; i++) q[i] = *(const f32x4*)(xr + i * 4);

    // prefetch BOTH GEMMs' step-0 B fragments (independent of As/Sx; their
    // L2 latency hides under the prologue + barrier)
    #pragma unroll
    for (int n = 0; n < 4; n++) {
      bvA[n] = *(const bf16x8*)(wA  + n * 1024 + lane * 16);
      cA[n]  = *(const bf16x8*)(wB2 + n * 1024 + lane * 16);
    }

    float vv[48];
    #pragma unroll
    for (int i = 0; i < 12; i++) {
      vv[4 * i] = q[i].x; vv[4 * i + 1] = q[i].y;
      vv[4 * i + 2] = q[i].z; vv[4 * i + 3] = q[i].w;
    }
    // LN stats
    float s = 0.f, sq = 0.f;
    #pragma unroll
    for (int i = 0; i < 48; i++) { s += vv[i]; sq += vv[i] * vv[i]; }
    #pragma unroll
    for (int off = 32; off >= 1; off >>= 1) {
      s  += __shfl_xor(s,  off);
      sq += __shfl_xor(sq, off);
    }
    float mean = s * (1.f / 3072.f);
    float var  = sq * (1.f / 3072.f) - mean * mean;
    float rstd = rsqrtf(var + EPSF);
    if (lane == 0) { st[2 * wid] = mean; st[2 * wid + 1] = rstd; }

    // As rows: lane holds k = lane*8..+8 for all 6 colors -> one b128 per row
    #pragma unroll
    for (int d = 0; d < 6; d++) {
      int row = wid * 6 + d;
      bf16x8 v;
      #pragma unroll
      for (int g = 0; g < 8; g++) v[g] = (short)f2bf_trunc(vv[g * 6 + d]);
      *(bf16x8*)(As + row * 1024 + ((lane ^ (row & 7)) << 4)) = v;
    }
    // Sx: raw color sums for the same 8 k
    bf16x8 sv;
    #pragma unroll
    for (int g = 0; g < 8; g++) {
      float ss = vv[g * 6] + vv[g * 6 + 1] + vv[g * 6 + 2] +
                 vv[g * 6 + 3] + vv[g * 6 + 4] + vv[g * 6 + 5];
      sv[g] = (short)f2bf_trunc(ss);
    }
    *(bf16x8*)(Sx + wid * 1024 + ((lane ^ (wid & 7)) << 4)) = sv;
  }
  __syncthreads();               // the ONLY barrier: As + Sx + st ready

  // ---- term2 FIRST: 8x512 over K=512; same-wave o-slice; result -> Ts ----
  {
    f32x4 acc2[4];
    #pragma unroll
    for (int n = 0; n < 4; n++) acc2[n] = (f32x4){0.f, 0.f, 0.f, 0.f};
    const int sxr = (co & 7);
    bf16x8 a2A, a2B;
    a2A = *(const bf16x8*)(Sx + sxr * 1024 + ((h ^ sxr) << 4));

    #pragma unroll 1
    for (int s = 0; s < 16; s += 2) {
      {
        int g6 = (s + 1) * 4 + h;
        a2B = *(const bf16x8*)(Sx + sxr * 1024 + ((g6 ^ sxr) << 4));
        const unsigned char* pn = wB2 + (size_t)(s + 1) * 4096;
        #pragma unroll
        for (int n = 0; n < 4; n++)
          cB[n] = *(const bf16x8*)(pn + n * 1024 + lane * 16);
      }
      __builtin_amdgcn_s_setprio(1);
      #pragma unroll
      for (int n = 0; n < 4; n++)
        acc2[n] = __builtin_amdgcn_mfma_f32_16x16x32_bf16(a2A, cA[n], acc2[n], 0, 0, 0);
      __builtin_amdgcn_s_setprio(0);
      if (s + 2 < 16) {
        int g6 = (s + 2) * 4 + h;
        a2A = *(const bf16x8*)(Sx + sxr * 1024 + ((g6 ^ sxr) << 4));
        const unsigned char* pn2 = wB2 + (size_t)(s + 2) * 4096;
        #pragma unroll
        for (int n = 0; n < 4; n++)
          cA[n] = *(const bf16x8*)(pn2 + n * 1024 + lane * 16);
      }
      __builtin_amdgcn_s_setprio(1);
      #pragma unroll
      for (int n = 0; n < 4; n++)
        acc2[n] = __builtin_amdgcn_mfma_f32_16x16x32_bf16(a2B, cB[n], acc2[n], 0, 0, 0);
      __builtin_amdgcn_s_setprio(0);
    }
    // rows 0..7 valid (positions); rows 8..15 are aliased duplicates - skip.
    if (h < 2) {
      #pragma unroll
      for (int n = 0; n < 4; n++)
        #pragma unroll
        for (int v = 0; v < 4; v++)
          Ts[(rvb + v) * TSS + wid * 64 + n * 16 + co] = acc2[n][v];
    }
  }
  // NO barrier: Ts slice [*, wid*64..+64] is written and read by wave wid only.

  // ---- term1: 48x512 over K=512; A and B register double-buffered ----
  f32x4 acc1[3][4];
  #pragma unroll
  for (int m = 0; m < 3; m++)
    #pragma unroll
    for (int n = 0; n < 4; n++) acc1[m][n] = (f32x4){0.f, 0.f, 0.f, 0.f};

  int arow[3], ar7[3];
  #pragma unroll
  for (int m = 0; m < 3; m++) {
    int row = m * 16 + co;
    arow[m] = row * 1024;  ar7[m] = row & 7;
  }

  {
    bf16x8 afA[3], afB[3];
    #pragma unroll
    for (int m = 0; m < 3; m++)               // step-0 A fragments
      afA[m] = *(const bf16x8*)(As + arow[m] + ((h ^ ar7[m]) << 4));

    #pragma unroll 1
    for (int s = 0; s < 16; s += 2) {
      // prefetch step s+1 (A from LDS, B from L2)
      {
        int g6 = (s + 1) * 4 + h;
        #pragma unroll
        for (int m = 0; m < 3; m++)
          afB[m] = *(const bf16x8*)(As + arow[m] + ((g6 ^ ar7[m]) << 4));
        const unsigned char* pn = wA + (size_t)(s + 1) * 4096;
        #pragma unroll
        for (int n = 0; n < 4; n++)
          bvB[n] = *(const bf16x8*)(pn + n * 1024 + lane * 16);
      }
      // MFMA step s
      __builtin_amdgcn_s_setprio(1);
      #pragma unroll
      for (int m = 0; m < 3; m++)
        #pragma unroll
        for (int n = 0; n < 4; n++)
          acc1[m][n] = __builtin_amdgcn_mfma_f32_16x16x32_bf16(afA[m], bvA[n], acc1[m][n], 0, 0, 0);
      __builtin_amdgcn_s_setprio(0);
      // prefetch step s+2
      if (s + 2 < 16) {
        int g6 = (s + 2) * 4 + h;
        #pragma unroll
        for (int m = 0; m < 3; m++)
          afA[m] = *(const bf16x8*)(As + arow[m] + ((g6 ^ ar7[m]) << 4));
        const unsigned char* pn2 = wA + (size_t)(s + 2) * 4096;
        #pragma unroll
        for (int n = 0; n < 4; n++)
          bvA[n] = *(const bf16x8*)(pn2 + n * 1024 + lane * 16);
      }
      // MFMA step s+1
      __builtin_amdgcn_s_setprio(1);
      #pragma unroll
      for (int m = 0; m < 3; m++)
        #pragma unroll
        for (int n = 0; n < 4; n++)
          acc1[m][n] = __builtin_amdgcn_mfma_f32_16x16x32_bf16(afB[m], bvB[n], acc1[m][n], 0, 0, 0);
      __builtin_amdgcn_s_setprio(0);
    }
  }

  // ---- epilogue: residual from As (LDS), direct wide stores ----
  #pragma unroll
  for (int n = 0; n < 4; n++) {
    const int o = wid * 64 + n * 16 + co;
    const float C1 = c12[o];          // L2-hot; loaded here to keep GEMM regs lean
    const float C2 = c12[KH + o];
    const int swzo = o >> 3;
    const int ob2 = (o & 7) * 2;
    #pragma unroll
    for (int m = 0; m < 3; m++) {
      int j0  = m * 16 + rvb;
      int pl0 = j0 / 6;
      int d0  = j0 - pl0 * 6;
      float mean0 = st[2 * pl0], rstd0 = st[2 * pl0 + 1];
      float t20   = Ts[pl0 * TSS + o];
      float cc0   = C1 - mean0 * rstd0 * C2;
      if (d0 < 3) {
        f32x4 ov;
        #pragma unroll
        for (int v = 0; v < 4; v++) {
          int j = j0 + v;
          unsigned short rx = *(const unsigned short*)(
              As + j * 1024 + ((swzo ^ (j & 7)) << 4) + ob2);
          ov[v] = bf2f(rx) + fmaxf(rstd0 * (acc1[m][n][v] + t20) + cc0, 0.f);
        }
        *(f32x4*)(out + (r0 + pl0) * DF + o * 6 + d0) = ov;
      } else {                               // d0 == 4: split 2 + 2
        int pl1 = pl0 + 1;
        float mean1 = st[2 * pl1], rstd1 = st[2 * pl1 + 1];
        float t21   = Ts[pl1 * TSS + o];
        float cc1   = C1 - mean1 * rstd1 * C2;
        f32x2 o0, o1;
        #pragma unroll
        for (int v = 0; v < 2; v++) {
          int j = j0 + v;
          unsigned short rx = *(const unsigned short*)(
              As + j * 1024 + ((swzo ^ (j & 7)) << 4) + ob2);
          o0[v] = bf2f(rx) + fmaxf(rstd0 * (acc1[m][n][v] + t20) + cc0, 0.f);
        }
        #pragma unroll
        for (int v = 2; v < 4; v++) {
          int j = j0 + v;
          unsigned short rx = *(const unsigned short*)(
              As + j * 1024 + ((swzo ^ (j & 7)) << 4) + ob2);
          o1[v - 2] = bf2f(rx) + fmaxf(rstd1 * (acc1[m][n][v] + t21) + cc1, 0.f);
        }
        *(f32x2*)(out + (r0 + pl0) * DF + o * 6 + 4) = o0;
        *(f32x2*)(out + (r0 + pl1) * DF + o * 6)     = o1;
      }
    }
  }
}

extern "C" void kernel_launch(void* const* d_in, const int* in_sizes, int n_in,
                              void* d_out, int out_size, void* d_ws, size_t ws_size,
                              hipStream_t stream) {
  (void)n_in; (void)out_size; (void)ws_size;
  const float* x  = (const float*)d_in[0];
  const float* cw = (const float*)d_in[1];
  const float* cb = (const float*)d_in[2];
  const float* nw = (const float*)d_in[3];
  const float* nb = (const float*)d_in[4];
  float* out = (float*)d_out;

  unsigned char* wbt = (unsigned char*)d_ws;                    // 1 MB images
  float* c12 = (float*)((char*)d_ws + (size_t)1024 * 1024);     // 4 KB

  prep_w<<<512, 256, 0, stream>>>(cw, cb, nw, nb, wbt, c12);

  const int R = in_sizes[0] / DF;            // 24576 positions
  fused_main<<<R / PPB, 512, 0, stream>>>(x, wbt, c12, out);
}